// Round 11
// baseline (15731.624 us; speedup 1.0000x reference)
//
#include <hip/hip_runtime.h>
#include <math.h>

#define DEVINL __device__ __forceinline__
typedef float f32x4 __attribute__((ext_vector_type(4)));

// ---------------------------------------------------------------------------
// RSSM scan, persistent single kernel, 256 WGs x 256 thr (1 WG/CU).
// R11 sync: grid barrier between every phase. Producers = PLAIN stores
// (vmcnt-ack => resident in local L2). Barrier: every WG arrives on a
// per-XCD counter (relaxed); the LAST arriver per XCD does a RELEASE
// fetch_add (compiler emits vmcnt; buffer_wbl2; vmcnt; add -> flushes the
// WHOLE XCD L2, all CUs' dirty lines) on a global counter; all WGs poll
// global == NOCC*phase. Consumers read intermediates via sc0/sc1 loads
// (bypass L1/L2 -> L3). R5 proved {plain-ish stores + wbl2-release + sc0sc1
// reads} correct; this aggregates 1024 wbl2/barrier -> 8.
// Census of WG->XCD mapping via HW_REG_XCC_ID (id 20, m09-verified).
// Phases/step: dyn | dynfin | gru | q0+x0 | qo256 | finx12. Prior chain
// batched after the scan. fp32 throughout (bf16 would flip argmaxes).
// ---------------------------------------------------------------------------

struct RPtrs {
  const float *embed, *action; const int *is_first;
  const float *W_in_deter, *b_in_deter, *g_in_deter;
  const float *W_in_stoch, *b_in_stoch, *g_in_stoch;
  const float *W_in_act,   *b_in_act,   *g_in_act;
  const float *W_dyn, *b_dyn, *g_dyn;
  const float *W_gru, *b_gru;
  const float *W_p0, *b_p0, *g_p0;
  const float *W_p1, *b_p1, *g_p1;
  const float *W_po, *b_po;
  const float *W_q0, *b_q0, *g_q0;
  const float *W_qo, *b_qo;
  float *out_post, *out_prior, *out_deters;
  float *deter, *determ, *xact, *hact;
  float *SDyn, *SQ0, *SX0, *Abuf0, *Abuf1;
  int *sidxg;
  unsigned *cns, *X, *G, *C0;
};

// ---- sc0/sc1 load helpers (consumer side) ---------------------------------
DEVINL void vm0() {
  asm volatile("s_waitcnt vmcnt(0)" ::: "memory");
  __builtin_amdgcn_sched_barrier(0);
}
DEVINL void ld2x4_issue(const float* p0, const float* p1, f32x4& r0, f32x4& r1) {
  asm volatile(
    "global_load_dwordx4 %0, %2, off sc0 sc1\n\t"
    "global_load_dwordx4 %1, %3, off sc0 sc1"
    : "=&v"(r0), "=&v"(r1) : "v"(p0), "v"(p1) : "memory");
}
DEVINL void ldsys8x4(const float* p0, const float* p1, const float* p2, const float* p3,
                     const float* p4, const float* p5, const float* p6, const float* p7,
                     f32x4& r0, f32x4& r1, f32x4& r2, f32x4& r3,
                     f32x4& r4, f32x4& r5, f32x4& r6, f32x4& r7) {
  asm volatile(
    "global_load_dwordx4 %0, %8, off sc0 sc1\n\t"
    "global_load_dwordx4 %1, %9, off sc0 sc1\n\t"
    "global_load_dwordx4 %2, %10, off sc0 sc1\n\t"
    "global_load_dwordx4 %3, %11, off sc0 sc1\n\t"
    "global_load_dwordx4 %4, %12, off sc0 sc1\n\t"
    "global_load_dwordx4 %5, %13, off sc0 sc1\n\t"
    "global_load_dwordx4 %6, %14, off sc0 sc1\n\t"
    "global_load_dwordx4 %7, %15, off sc0 sc1\n\t"
    "s_waitcnt vmcnt(0)"
    : "=&v"(r0), "=&v"(r1), "=&v"(r2), "=&v"(r3),
      "=&v"(r4), "=&v"(r5), "=&v"(r6), "=&v"(r7)
    : "v"(p0), "v"(p1), "v"(p2), "v"(p3), "v"(p4), "v"(p5), "v"(p6), "v"(p7)
    : "memory");
}
DEVINL void ldsys8s(const float* p0, const float* p1, const float* p2, const float* p3,
                    const float* p4, const float* p5, const float* p6, const float* p7,
                    float& r0, float& r1, float& r2, float& r3,
                    float& r4, float& r5, float& r6, float& r7) {
  asm volatile(
    "global_load_dword %0, %8, off sc0 sc1\n\t"
    "global_load_dword %1, %9, off sc0 sc1\n\t"
    "global_load_dword %2, %10, off sc0 sc1\n\t"
    "global_load_dword %3, %11, off sc0 sc1\n\t"
    "global_load_dword %4, %12, off sc0 sc1\n\t"
    "global_load_dword %5, %13, off sc0 sc1\n\t"
    "global_load_dword %6, %14, off sc0 sc1\n\t"
    "global_load_dword %7, %15, off sc0 sc1\n\t"
    "s_waitcnt vmcnt(0)"
    : "=&v"(r0), "=&v"(r1), "=&v"(r2), "=&v"(r3),
      "=&v"(r4), "=&v"(r5), "=&v"(r6), "=&v"(r7)
    : "v"(p0), "v"(p1), "v"(p2), "v"(p3), "v"(p4), "v"(p5), "v"(p6), "v"(p7)
    : "memory");
}
DEVINL float ldsysf(const float* p) {
  float r;
  asm volatile("global_load_dword %0, %1, off sc0 sc1\n\ts_waitcnt vmcnt(0)"
               : "=&v"(r) : "v"(p) : "memory");
  return r;
}
DEVINL int ldsysi(const int* p) {
  int r;
  asm volatile("global_load_dword %0, %1, off sc0 sc1\n\ts_waitcnt vmcnt(0)"
               : "=&v"(r) : "v"(p) : "memory");
  return r;
}

// ---- aggregated-flush grid barrier ----------------------------------------
DEVINL void gbar(const RPtrs& p, int xcd, unsigned myC, unsigned NOCC, unsigned ph) {
  vm0();                 // this wave's plain stores ack'd (resident in L2)
  __syncthreads();       // all 4 waves done
  if (threadIdx.x == 0) {
    unsigned old = __hip_atomic_fetch_add(p.X + (size_t)xcd * 64, 1u,
                                          __ATOMIC_RELAXED, __HIP_MEMORY_SCOPE_AGENT);
    if (old == myC * ph - 1u)   // last WG on this XCD this phase
      __hip_atomic_fetch_add(p.G, 1u, __ATOMIC_RELEASE,
                             __HIP_MEMORY_SCOPE_AGENT);   // vmcnt;wbl2;vmcnt;add
    while (__hip_atomic_load(p.G, __ATOMIC_RELAXED, __HIP_MEMORY_SCOPE_AGENT)
           < NOCC * ph)
      __builtin_amdgcn_s_sleep(2);
  }
  __syncthreads();
}

// ---- A loaders ------------------------------------------------------------
struct LdPlain {
  const float* A; int lda;
  DEVINL const float* addr(int r, int k) const { return A + (size_t)r * lda + k; }
};
struct LdDyn {   // [dg(256 masked deter) | x(3072 activated)]
  const float* dm; const float* x; int blk;
  DEVINL const float* addr(int r, int k) const {
    return (k < 256) ? dm + (size_t)r * 2048 + blk * 256 + k
                     : x + (size_t)r * 3072 + (k - 256);
  }
};
struct LdQ0 {    // [deter(2048) | embed(1024)]
  const float* det; const float* emb; int t;
  DEVINL const float* addr(int r, int k) const {
    return (k < 2048) ? det + (size_t)r * 2048 + k
                      : emb + ((size_t)r * 64 + t) * 1024 + (k - 2048);
  }
};

#define FMA4(A, S, W) { (A)[0]=fmaf((S),(W)[0],(A)[0]); (A)[1]=fmaf((S),(W)[1],(A)[1]); \
                        (A)[2]=fmaf((S),(W)[2],(A)[2]); (A)[3]=fmaf((S),(W)[3],(A)[3]); }

DEVINL void fma_block(const float* __restrict__ Wp, int ldw,
                      const float* __restrict__ AsRg, f32x4* acc) {
#pragma unroll 8
  for (int kk = 0; kk < 64; ++kk) {
    f32x4 w = *(const f32x4*)(Wp + (size_t)kk * ldw);
    const float* Ab = AsRg + kk * 36;
    f32x4 alo = *(const f32x4*)(Ab);
    f32x4 ahi = *(const f32x4*)(Ab + 4);
    FMA4(acc[0], alo[0], w); FMA4(acc[1], alo[1], w);
    FMA4(acc[2], alo[2], w); FMA4(acc[3], alo[3], w);
    FMA4(acc[4], ahi[0], w); FMA4(acc[5], ahi[1], w);
    FMA4(acc[6], ahi[2], w); FMA4(acc[7], ahi[3], w);
  }
}

// ---- GEMM: 256 cols x 32 rows x (NBLK*64) K; sys-A, plain-W, plain-out ----
template <int NBLK, typename LA>
DEVINL void gemm_tile(LA la, const float* __restrict__ W, int ldw, int wcb,
                      int k0, float* __restrict__ slab, int sst, int scb,
                      const float* __restrict__ bias, float* As) {
  const int tid = threadIdx.x;
  const int c4 = (tid & 63) * 4;
  const int rg = (tid >> 6) * 8;
  const int srr = tid & 31;
  const int skk = (tid >> 5) * 8;
  f32x4 acc[8];
#pragma unroll
  for (int i = 0; i < 8; ++i) acc[i] = (f32x4){0.f, 0.f, 0.f, 0.f};
  f32x4 a0 = (f32x4){0.f,0.f,0.f,0.f}, a1 = a0, b0v = a0, b1v = a0;
  { const float* ap = la.addr(srr, k0 + skk); ld2x4_issue(ap, ap + 4, a0, a1); }
  if (NBLK == 2) {
    const float* ap = la.addr(srr, k0 + 64 + skk);
    ld2x4_issue(ap, ap + 4, b0v, b1v);
  }
  vm0();                          // all staged A data in registers
  __syncthreads();
#pragma unroll
  for (int e = 0; e < 4; ++e) {
    As[(skk + e) * 36 + srr]     = a0[e];
    As[(skk + 4 + e) * 36 + srr] = a1[e];
  }
  __syncthreads();
  fma_block(W + (size_t)k0 * ldw + wcb + c4, ldw, As + rg, acc);
  if (NBLK == 2) {
    __syncthreads();
#pragma unroll
    for (int e = 0; e < 4; ++e) {
      As[(skk + e) * 36 + srr]     = b0v[e];
      As[(skk + 4 + e) * 36 + srr] = b1v[e];
    }
    __syncthreads();
    fma_block(W + (size_t)(k0 + 64) * ldw + wcb + c4, ldw, As + rg, acc);
  }
  f32x4 bv = (f32x4){0.f, 0.f, 0.f, 0.f};
  if (bias) bv = *(const f32x4*)(bias + wcb + c4);
#pragma unroll
  for (int i = 0; i < 8; ++i) {
    f32x4 o = acc[i] + bv;
    *(f32x4*)(slab + (size_t)(rg + i) * sst + scb + c4) = o;
  }
}

// ---- epilogue GEMM: full-K (nblk runtime), direct out ---------------------
template <typename LA>
DEVINL void gemm_big(LA la, const float* __restrict__ W, int ldw, int wcb,
                     int nblk, float* __restrict__ outp, int ost,
                     const float* __restrict__ bias, float* As) {
  const int tid = threadIdx.x;
  const int c4 = (tid & 63) * 4;
  const int rg = (tid >> 6) * 8;
  const int srr = tid & 31;
  const int skk = (tid >> 5) * 8;
  f32x4 acc[8];
#pragma unroll
  for (int i = 0; i < 8; ++i) acc[i] = (f32x4){0.f, 0.f, 0.f, 0.f};
  for (int b = 0; b < nblk; ++b) {
    f32x4 a0, a1;
    { const float* ap = la.addr(srr, b * 64 + skk); ld2x4_issue(ap, ap + 4, a0, a1); }
    vm0();
    __syncthreads();
#pragma unroll
    for (int e = 0; e < 4; ++e) {
      As[(skk + e) * 36 + srr]     = a0[e];
      As[(skk + 4 + e) * 36 + srr] = a1[e];
    }
    __syncthreads();
    fma_block(W + (size_t)(b * 64) * ldw + wcb + c4, ldw, As + rg, acc);
  }
  f32x4 bv = *(const f32x4*)(bias + wcb + c4);
#pragma unroll
  for (int i = 0; i < 8; ++i) {
    f32x4 o = acc[i] + bv;
    *(f32x4*)(outp + (size_t)(rg + i) * ost + wcb + c4) = o;
  }
}

// ---- chunk-sum helper (sys loads, ascending, clamped) ---------------------
DEVINL f32x4 sum8(const float* b0, size_t cstr, int ch, int nch, f32x4 y) {
  const float* q0 = b0 + (size_t)ch * cstr;
  const float* q1 = b0 + (size_t)(ch + 1 < nch ? ch + 1 : nch - 1) * cstr;
  const float* q2 = b0 + (size_t)(ch + 2 < nch ? ch + 2 : nch - 1) * cstr;
  const float* q3 = b0 + (size_t)(ch + 3 < nch ? ch + 3 : nch - 1) * cstr;
  const float* q4 = b0 + (size_t)(ch + 4 < nch ? ch + 4 : nch - 1) * cstr;
  const float* q5 = b0 + (size_t)(ch + 5 < nch ? ch + 5 : nch - 1) * cstr;
  const float* q6 = b0 + (size_t)(ch + 6 < nch ? ch + 6 : nch - 1) * cstr;
  const float* q7 = b0 + (size_t)(ch + 7 < nch ? ch + 7 : nch - 1) * cstr;
  f32x4 v0, v1, v2, v3, v4, v5, v6, v7;
  ldsys8x4(q0, q1, q2, q3, q4, q5, q6, q7, v0, v1, v2, v3, v4, v5, v6, v7);
  y += v0;
  if (ch + 1 < nch) y += v1;
  if (ch + 2 < nch) y += v2;
  if (ch + 3 < nch) y += v3;
  if (ch + 4 < nch) y += v4;
  if (ch + 5 < nch) y += v5;
  if (ch + 6 < nch) y += v6;
  if (ch + 7 < nch) y += v7;
  return y;
}

// ---- finalizer: sum chunks (sys), RMS, SiLU, plain out --------------------
DEVINL void act_fin(const float* slab, int N, int nch, int r,
                    const float* __restrict__ g, float* __restrict__ out,
                    float invN, float* red) {
  const int tid = threadIdx.x;
  const size_t cstr = (size_t)32 * N;
  const float* base = slab + (size_t)r * N;
  f32x4 y0 = (f32x4){0.f, 0.f, 0.f, 0.f}, y1 = y0;
  for (int ch = 0; ch < nch; ch += 8)
    y0 = sum8(base + tid * 4, cstr, ch, nch, y0);
  float ss = y0[0]*y0[0] + y0[1]*y0[1] + y0[2]*y0[2] + y0[3]*y0[3];
  if (N == 2048) {
    for (int ch = 0; ch < nch; ch += 8)
      y1 = sum8(base + 1024 + tid * 4, cstr, ch, nch, y1);
    ss += y1[0]*y1[0] + y1[1]*y1[1] + y1[2]*y1[2] + y1[3]*y1[3];
  }
#pragma unroll
  for (int o = 32; o > 0; o >>= 1) ss += __shfl_down(ss, o, 64);
  if ((tid & 63) == 0) red[tid >> 6] = ss;
  __syncthreads();
  if (tid == 0)
    red[4] = 1.f / sqrtf((red[0] + red[1] + red[2] + red[3]) * invN + 1e-6f);
  __syncthreads();
  const float sc = red[4];
  {
    f32x4 gg = *(const f32x4*)(g + tid * 4);
    f32x4 v = y0 * sc * gg;
#pragma unroll
    for (int k = 0; k < 4; ++k) v[k] = v[k] / (1.f + expf(-v[k]));
    *(f32x4*)(out + tid * 4) = v;
  }
  if (N == 2048) {
    f32x4 gg = *(const f32x4*)(g + 1024 + tid * 4);
    f32x4 v = y1 * sc * gg;
#pragma unroll
    for (int k = 0; k < 4; ++k) v[k] = v[k] / (1.f + expf(-v[k]));
    *(f32x4*)(out + 1024 + tid * 4) = v;
  }
  __syncthreads();
}

DEVINL float sigm(float x) { return 1.f / (1.f + expf(-x)); }

// ---- x2 (action) pre-act + RMS + SiLU for row r, step tt (plain) ----------
DEVINL void x2_row(const RPtrs& p, int tt, int r, float m, float* red) {
  const int tid = threadIdx.x;
  const int c0 = tid * 4;
  const float* arow = p.action + ((size_t)r * 64 + tt) * 16;
  f32x4 s2 = *(const f32x4*)(p.b_in_act + c0);
#pragma unroll
  for (int ii = 0; ii < 16; ++ii) {
    float av = arow[ii] * m;
    av = av / fmaxf(fabsf(av), 1.f);
    f32x4 wv = *(const f32x4*)(p.W_in_act + ii * 1024 + c0);
    FMA4(s2, av, wv);
  }
  float ss = s2[0]*s2[0] + s2[1]*s2[1] + s2[2]*s2[2] + s2[3]*s2[3];
#pragma unroll
  for (int o = 32; o > 0; o >>= 1) ss += __shfl_down(ss, o, 64);
  if ((tid & 63) == 0) red[tid >> 6] = ss;
  __syncthreads();
  if (tid == 0)
    red[4] = 1.f / sqrtf((red[0] + red[1] + red[2] + red[3]) * (1.f / 1024.f) + 1e-6f);
  __syncthreads();
  float sc = red[4];
  f32x4 gg = *(const f32x4*)(p.g_in_act + c0);
  f32x4 v = s2 * sc * gg;
#pragma unroll
  for (int k = 0; k < 4; ++k) v[k] = v[k] / (1.f + expf(-v[k]));
  *(f32x4*)(p.xact + (size_t)r * 3072 + 2048 + c0) = v;
  __syncthreads();
}

// ---- bias-only pre-act + RMS + SiLU (t=0) ---------------------------------
DEVINL void bias_row(const float* __restrict__ b, const float* __restrict__ g,
                     float* __restrict__ out, float* red) {
  const int tid = threadIdx.x;
  const int c0 = tid * 4;
  f32x4 pre = *(const f32x4*)(b + c0);
  float ss = pre[0]*pre[0] + pre[1]*pre[1] + pre[2]*pre[2] + pre[3]*pre[3];
#pragma unroll
  for (int o = 32; o > 0; o >>= 1) ss += __shfl_down(ss, o, 64);
  if ((tid & 63) == 0) red[tid >> 6] = ss;
  __syncthreads();
  if (tid == 0)
    red[4] = 1.f / sqrtf((red[0] + red[1] + red[2] + red[3]) * (1.f / 1024.f) + 1e-6f);
  __syncthreads();
  float sc = red[4];
  f32x4 gg = *(const f32x4*)(g + c0);
  f32x4 v = pre * sc * gg;
#pragma unroll
  for (int k = 0; k < 4; ++k) v[k] = v[k] / (1.f + expf(-v[k]));
  *(f32x4*)(out + c0) = v;
  __syncthreads();
}

// ---- gru: full K=256 dot + gates + state update ---------------------------
DEVINL void gru_body(const RPtrs& p, int t, int wg, float* Al) {
  const int blk = wg >> 4, jch = wg & 15;
  const int tid = threadIdx.x;
  {
    const float* hp = p.hact + blk * 256 + tid;
    for (int jb = 0; jb < 32; jb += 8) {
      float v0, v1, v2, v3, v4, v5, v6, v7;
      ldsys8s(hp + (size_t)(jb + 0) * 2048, hp + (size_t)(jb + 1) * 2048,
              hp + (size_t)(jb + 2) * 2048, hp + (size_t)(jb + 3) * 2048,
              hp + (size_t)(jb + 4) * 2048, hp + (size_t)(jb + 5) * 2048,
              hp + (size_t)(jb + 6) * 2048, hp + (size_t)(jb + 7) * 2048,
              v0, v1, v2, v3, v4, v5, v6, v7);
      Al[tid * 34 + jb + 0] = v0; Al[tid * 34 + jb + 1] = v1;
      Al[tid * 34 + jb + 2] = v2; Al[tid * 34 + jb + 3] = v3;
      Al[tid * 34 + jb + 4] = v4; Al[tid * 34 + jb + 5] = v5;
      Al[tid * 34 + jb + 6] = v6; Al[tid * 34 + jb + 7] = v7;
    }
  }
  __syncthreads();
  const int j = tid & 15, rg = tid >> 4;
  const int r0 = rg * 2;
  const int jcol = jch * 16 + j;
  const float* Wg = p.W_gru + (size_t)blk * 196608 + jcol;
  float r0a = 0, r1a = 0, c0a = 0, c1a = 0, u0a = 0, u1a = 0;
#pragma unroll 4
  for (int kk = 0; kk < 256; ++kk) {
    float wr = Wg[(size_t)kk * 768];
    float wc = Wg[(size_t)kk * 768 + 256];
    float wu = Wg[(size_t)kk * 768 + 512];
    float ax = Al[kk * 34 + r0], ay = Al[kk * 34 + r0 + 1];
    r0a = fmaf(ax, wr, r0a); r1a = fmaf(ay, wr, r1a);
    c0a = fmaf(ax, wc, c0a); c1a = fmaf(ay, wc, c1a);
    u0a = fmaf(ax, wu, u0a); u1a = fmaf(ay, wu, u1a);
  }
  const int col = blk * 256 + jcol;
  const float br = p.b_gru[blk * 768 + jcol];
  const float bc = p.b_gru[blk * 768 + 256 + jcol];
  const float bu = p.b_gru[blk * 768 + 512 + jcol];
#pragma unroll
  for (int rr = 0; rr < 2; ++rr) {
    int r = r0 + rr;
    float gr = (rr ? r1a : r0a) + br;
    float gc = (rr ? c1a : c0a) + bc;
    float gu = (rr ? u1a : u0a) + bu;
    float rs = sigm(gr);
    float cc = tanhf(rs * gc);
    float uu = sigm(gu - 1.f);
    float dg = ldsysf(p.determ + (size_t)r * 2048 + col);
    float nd = uu * cc + (1.f - uu) * dg;
    p.deter[(size_t)r * 2048 + col] = nd;
    p.out_deters[((size_t)r * 64 + t) * 2048 + col] = nd;
    float mn = 0.f;
    if (t + 1 < 64) mn = p.is_first[r * 64 + (t + 1)] ? 0.f : 1.f;
    p.determ[(size_t)r * 2048 + col] = nd * mn;
  }
  __syncthreads();
}

// ---- qo256: q0fin (redundant x8) + chunked GEMV + local argmax ------------
DEVINL void qo_body(const RPtrs& p, int t, int wg, float* smem) {
  float* qrow = smem;             // 1024
  float* pbuf = smem + 1024;      // 1024
  float* ybuf = smem + 2048;      // 128
  float* red  = smem + 2176;      // 8
  const int r = wg >> 3, ch = wg & 7;
  const int tid = threadIdx.x;
  const int c0 = tid * 4;
  {  // q0fin -> qrow
    const float* base = p.SQ0 + (size_t)r * 1024 + c0;
    f32x4 y = (f32x4){0.f, 0.f, 0.f, 0.f};
    y = sum8(base, 32768, 0, 24, y);
    y = sum8(base, 32768, 8, 24, y);
    y = sum8(base, 32768, 16, 24, y);
    float ss = y[0]*y[0] + y[1]*y[1] + y[2]*y[2] + y[3]*y[3];
#pragma unroll
    for (int o = 32; o > 0; o >>= 1) ss += __shfl_down(ss, o, 64);
    if ((tid & 63) == 0) red[tid >> 6] = ss;
    __syncthreads();
    if (tid == 0)
      red[4] = 1.f / sqrtf((red[0] + red[1] + red[2] + red[3]) * (1.f / 1024.f) + 1e-6f);
    __syncthreads();
    float sc = red[4];
    f32x4 gg = *(const f32x4*)(p.g_q0 + c0);
    f32x4 v = y * sc * gg;
#pragma unroll
    for (int k = 0; k < 4; ++k) v[k] = v[k] / (1.f + expf(-v[k]));
    *(f32x4*)(qrow + c0) = v;
  }
  __syncthreads();
  const int cg = tid & 31, ks = tid >> 5;
  const int col0 = ch * 128 + cg * 4;
  {  // GEMV k-partials (W_qo read once per chunk, shared by 32 row-WGs in L2)
    f32x4 acc = (f32x4){0.f, 0.f, 0.f, 0.f};
    const float* Wq = p.W_qo + col0;
    const float* qr = qrow + ks * 128;
#pragma unroll 8
    for (int k = 0; k < 128; ++k) {
      f32x4 wv = *(const f32x4*)(Wq + (size_t)(ks * 128 + k) * 1024);
      FMA4(acc, qr[k], wv);
    }
    *(f32x4*)(pbuf + (ks * 32 + cg) * 4) = acc;
  }
  __syncthreads();
  if (tid < 32) {
    f32x4 s = *(const f32x4*)(p.b_qo + ch * 128 + tid * 4);
#pragma unroll
    for (int k2 = 0; k2 < 8; ++k2) s += *(const f32x4*)(pbuf + (k2 * 32 + tid) * 4);
    *(f32x4*)(p.out_post + ((size_t)r * 64 + t) * 1024 + ch * 128 + tid * 4) = s;
    *(f32x4*)(ybuf + tid * 4) = s;
  }
  __syncthreads();
  if (t < 63 && tid < 4) {   // groups g = ch*4 + tid (32 cols each, local)
    const float* rb = ybuf + tid * 32;
    float best = rb[0]; int bi = 0;
#pragma unroll
    for (int c = 1; c < 32; ++c) {
      float v = rb[c];
      if (v > best) { best = v; bi = c; }   // strict > keeps first index
    }
    p.sidxg[r * 32 + ch * 4 + tid] = bi;    // plain store
  }
  __syncthreads();
}

// ---- finx12: x1/x2(t+1) (WGs 0-31) | x0fin(t+1) (WGs 32-63) ---------------
DEVINL void x12_fin(const RPtrs& p, int t, int wg, float* smem, int* sidx) {
  const int tid = threadIdx.x;
  if (wg >= 32) {
    act_fin(p.SX0, 1024, 16, wg - 32, p.g_in_deter,
            p.xact + (size_t)(wg - 32) * 3072, 1.f / 1024.f, smem);
    return;
  }
  const int r = wg;
  if (tid < 32) sidx[tid] = ldsysi(p.sidxg + r * 32 + tid) & 31;
  __syncthreads();
  const float m = p.is_first[r * 64 + t + 1] ? 0.f : 1.f;
  const int c0 = tid * 4;
  f32x4 s1 = (f32x4){0.f, 0.f, 0.f, 0.f};
  if (m != 0.f) {
    for (int g = 0; g < 32; ++g)
      s1 += *(const f32x4*)(p.W_in_stoch + (size_t)(g * 32 + sidx[g]) * 1024 + c0);
  }
  f32x4 pre = *(const f32x4*)(p.b_in_stoch + c0) + s1 * m;
  float ss = pre[0]*pre[0] + pre[1]*pre[1] + pre[2]*pre[2] + pre[3]*pre[3];
#pragma unroll
  for (int o = 32; o > 0; o >>= 1) ss += __shfl_down(ss, o, 64);
  if ((tid & 63) == 0) smem[tid >> 6] = ss;
  __syncthreads();
  if (tid == 0)
    smem[4] = 1.f / sqrtf((smem[0] + smem[1] + smem[2] + smem[3]) * (1.f / 1024.f) + 1e-6f);
  __syncthreads();
  {
    float sc = smem[4];
    f32x4 gg = *(const f32x4*)(p.g_in_stoch + c0);
    f32x4 v = pre * sc * gg;
#pragma unroll
    for (int k = 0; k < 4; ++k) v[k] = v[k] / (1.f + expf(-v[k]));
    *(f32x4*)(p.xact + (size_t)r * 3072 + 1024 + c0) = v;
  }
  __syncthreads();
  x2_row(p, t + 1, r, m, smem);
}

// ===========================================================================
__global__ __launch_bounds__(256, 2) void rssm_persist(RPtrs p) {
  const int wg = blockIdx.x;
  const int tid = threadIdx.x;
  __shared__ __align__(16) float smem[8704];
  __shared__ int sidx[32];
  __shared__ unsigned scc[2];

  // HW_REG_XCC_ID = id 20, offset 0, size 32 -> imm = (31<<11)|(0<<6)|20
  int xcd = __builtin_amdgcn_s_getreg((31 << 11) | (0 << 6) | 20) & 7;

  // ---- census (atomics are L3-coherent; no flush needed) ----
  if (tid == 0) {
    __hip_atomic_fetch_add(p.cns + (size_t)xcd * 64, 1u, __ATOMIC_RELAXED,
                           __HIP_MEMORY_SCOPE_AGENT);
    __hip_atomic_fetch_add(p.C0, 1u, __ATOMIC_RELAXED, __HIP_MEMORY_SCOPE_AGENT);
    while (__hip_atomic_load(p.C0, __ATOMIC_RELAXED, __HIP_MEMORY_SCOPE_AGENT) < 256u)
      __builtin_amdgcn_s_sleep(2);
    unsigned myC = __hip_atomic_load(p.cns + (size_t)xcd * 64, __ATOMIC_RELAXED,
                                     __HIP_MEMORY_SCOPE_AGENT);
    unsigned nocc = 0;
    for (int i = 0; i < 8; ++i)
      nocc += (__hip_atomic_load(p.cns + (size_t)i * 64, __ATOMIC_RELAXED,
                                 __HIP_MEMORY_SCOPE_AGENT) != 0u) ? 1u : 0u;
    scc[0] = myC; scc[1] = nocc;
  }
  __syncthreads();
  const unsigned myC = scc[0], NOCC = scc[1];
  unsigned ph = 0;

  // ---- prologue: xact(0) (determ=0, stoch=0 -> bias rows) ----
  if (wg < 32) {
    bias_row(p.b_in_deter, p.g_in_deter, p.xact + (size_t)wg * 3072, smem);
    bias_row(p.b_in_stoch, p.g_in_stoch, p.xact + (size_t)wg * 3072 + 1024, smem);
    float m = p.is_first[wg * 64] ? 0.f : 1.f;
    x2_row(p, 0, wg, m, smem);
  }
  gbar(p, xcd, myC, NOCC, ++ph);

#pragma unroll 1
  for (int t = 0; t < 64; ++t) {
    // P1: dyn (208)
    if (wg < 208) {
      int blk = wg / 26, kc = wg % 26;
      LdDyn la{p.determ, p.xact, blk};
      gemm_tile<2>(la, p.W_dyn + (size_t)blk * 851968, 256, 0, kc * 128,
                   p.SDyn + (size_t)kc * 65536, 2048, blk * 256,
                   kc == 0 ? p.b_dyn + blk * 256 : nullptr, smem);
    }
    gbar(p, xcd, myC, NOCC, ++ph);
    // P2: dynfin (32)
    if (wg < 32)
      act_fin(p.SDyn, 2048, 26, wg, p.g_dyn, p.hact + (size_t)wg * 2048,
              1.f / 2048.f, smem);
    gbar(p, xcd, myC, NOCC, ++ph);
    // P3: gru (128)
    if (wg < 128) gru_body(p, t, wg, smem);
    gbar(p, xcd, myC, NOCC, ++ph);
    // P4: q0 (96) + x0(t+1) (64)
    if (wg < 96) {
      int ct = wg & 3, kc = wg >> 2;
      LdQ0 la{p.deter, p.embed, t};
      gemm_tile<2>(la, p.W_q0, 1024, ct * 256, kc * 128,
                   p.SQ0 + (size_t)kc * 32768, 1024, ct * 256,
                   kc == 0 ? p.b_q0 : nullptr, smem);
    } else if (wg < 160 && t < 63) {
      int i = wg - 96, ct = i & 3, kc = i >> 2;
      LdPlain la{p.determ, 2048};
      gemm_tile<2>(la, p.W_in_deter, 1024, ct * 256, kc * 128,
                   p.SX0 + (size_t)kc * 32768, 1024, ct * 256,
                   kc == 0 ? p.b_in_deter : nullptr, smem);
    }
    gbar(p, xcd, myC, NOCC, ++ph);
    // P5: qo256 (all 256)
    qo_body(p, t, wg, smem);
    gbar(p, xcd, myC, NOCC, ++ph);
    // P6: finx12 (64)
    if (t < 63 && wg < 64) x12_fin(p, t, wg, smem, sidx);
    gbar(p, xcd, myC, NOCC, ++ph);
  }

  // ---- epilogue: batched prior over 2048 rows ----
  {
    int rb = wg >> 2, ct = wg & 3;
    LdPlain la{p.out_deters + (size_t)rb * 65536, 2048};
    gemm_big(la, p.W_p0, 1024, ct * 256, 32,
             p.Abuf0 + (size_t)rb * 32768, 1024, p.b_p0, smem);
  }
  gbar(p, xcd, myC, NOCC, ++ph);
  for (int i = 0; i < 8; ++i)
    act_fin(p.Abuf0, 1024, 1, wg + i * 256, p.g_p0,
            p.Abuf1 + (size_t)(wg + i * 256) * 1024, 1.f / 1024.f, smem);
  gbar(p, xcd, myC, NOCC, ++ph);
  {
    int rb = wg >> 2, ct = wg & 3;
    LdPlain la{p.Abuf1 + (size_t)rb * 32768, 1024};
    gemm_big(la, p.W_p1, 1024, ct * 256, 16,
             p.Abuf0 + (size_t)rb * 32768, 1024, p.b_p1, smem);
  }
  gbar(p, xcd, myC, NOCC, ++ph);
  for (int i = 0; i < 8; ++i)
    act_fin(p.Abuf0, 1024, 1, wg + i * 256, p.g_p1,
            p.Abuf1 + (size_t)(wg + i * 256) * 1024, 1.f / 1024.f, smem);
  gbar(p, xcd, myC, NOCC, ++ph);
  {
    int rb = wg >> 2, ct = wg & 3;
    LdPlain la{p.Abuf1 + (size_t)rb * 32768, 1024};
    gemm_big(la, p.W_po, 1024, ct * 256, 16,
             p.out_prior + (size_t)rb * 32768, 1024, p.b_po, smem);
  }
  // kernel end: implicit device flush makes out_* visible to host
}

// ===========================================================================
extern "C" void kernel_launch(void* const* d_in, const int* in_sizes, int n_in,
                              void* d_out, int out_size, void* d_ws,
                              size_t ws_size, hipStream_t stream) {
  RPtrs p;
  p.embed      = (const float*)d_in[0];
  p.action     = (const float*)d_in[1];
  p.is_first   = (const int*)d_in[2];
  p.W_in_deter = (const float*)d_in[3];  p.b_in_deter = (const float*)d_in[4];  p.g_in_deter = (const float*)d_in[5];
  p.W_in_stoch = (const float*)d_in[6];  p.b_in_stoch = (const float*)d_in[7];  p.g_in_stoch = (const float*)d_in[8];
  p.W_in_act   = (const float*)d_in[9];  p.b_in_act   = (const float*)d_in[10]; p.g_in_act   = (const float*)d_in[11];
  p.W_dyn      = (const float*)d_in[12]; p.b_dyn      = (const float*)d_in[13]; p.g_dyn      = (const float*)d_in[14];
  p.W_gru      = (const float*)d_in[15]; p.b_gru      = (const float*)d_in[16];
  p.W_p0       = (const float*)d_in[17]; p.b_p0       = (const float*)d_in[18]; p.g_p0       = (const float*)d_in[19];
  p.W_p1       = (const float*)d_in[20]; p.b_p1       = (const float*)d_in[21]; p.g_p1       = (const float*)d_in[22];
  p.W_po       = (const float*)d_in[23]; p.b_po       = (const float*)d_in[24];
  p.W_q0       = (const float*)d_in[25]; p.b_q0       = (const float*)d_in[26]; p.g_q0       = (const float*)d_in[27];
  p.W_qo       = (const float*)d_in[28]; p.b_qo       = (const float*)d_in[29];

  float* o = (float*)d_out;
  p.out_post   = o;               // [32][64][1024]
  p.out_prior  = o + 2097152;     // [32][64][1024]
  p.out_deters = o + 4194304;     // [32][64][2048]

  float* w = (float*)d_ws;
  // loop-era layout:
  p.deter  = w;                   // 65536
  p.determ = w + 65536;           // 65536
  p.xact   = w + 131072;          // 98304   [32][3072]
  p.hact   = w + 229376;          // 65536
  p.SDyn   = w + 393216;          // 1703936 [26][32][2048]
  p.SQ0    = w + 2097152;         // 786432  [24][32][1024]
  p.SX0    = w + 2883584;         // 524288  [16][32][1024]
  // epilogue-era (overlaps loop buffers; epilogue reads are sc0sc1):
  p.Abuf0  = w;                   // 2097152 [2048][1024]
  p.Abuf1  = w + 2097152;         // 2097152 [2048][1024] (ends at 4194304)
  p.sidxg  = (int*)(w + 4194304);        // 1024
  p.cns    = (unsigned*)(w + 4195328);   // 8*64
  p.X      = (unsigned*)(w + 4195840);   // 8*64
  p.G      = (unsigned*)(w + 4196352);   // 64
  p.C0     = (unsigned*)(w + 4196416);   // 64
  // total 4196480 floats ~= 16.8 MB

  hipMemsetAsync(w, 0, 131072 * 4, stream);               // deter + determ
  hipMemsetAsync(w + 4194304, 0, 2176 * 4, stream);       // sidx + counters
  rssm_persist<<<256, 256, 0, stream>>>(p);
}

// Round 12
// 6941.550 us; speedup vs baseline: 2.2663x; 2.2663x over previous
//
#include <hip/hip_runtime.h>
#include <math.h>

#define DEVINL __device__ __forceinline__
typedef float f32x4 __attribute__((ext_vector_type(4)));

// ---------------------------------------------------------------------------
// RSSM scan, multi-launch. R12: 6 launches/step (R9 was 7):
//   dyn | dynfin | gru | q0+x0 | qo256(q0fin+GEMV+argmax) | finx12
// Persistent-sync abandoned for good: correct in-kernel release (wbl2) costs
// >=30us/barrier (R5/R11 measurements) > 12us launch gap; relaxed sync is
// unsound on gfx950 (R7). Launch boundaries = only sync; plain loads/stores.
// qo256: each WG = (row, 128-col chunk); reads 0.5MB of W_qo (not 4MB - R10's
// mistake); q0-row finalize recomputed redundantly per chunk; argmax local.
// Prior chain (p0/p1/po) batched M=2048 after the scan (R9). fp32 throughout
// (bf16 would flip argmaxes -> cascading recurrence error).
// ---------------------------------------------------------------------------

struct RPtrs {
  const float *embed, *action; const int *is_first;
  const float *W_in_deter, *b_in_deter, *g_in_deter;
  const float *W_in_stoch, *b_in_stoch, *g_in_stoch;
  const float *W_in_act,   *b_in_act,   *g_in_act;
  const float *W_dyn, *b_dyn, *g_dyn;
  const float *W_gru, *b_gru;
  const float *W_p0, *b_p0, *g_p0;
  const float *W_p1, *b_p1, *g_p1;
  const float *W_po, *b_po;
  const float *W_q0, *b_q0, *g_q0;
  const float *W_qo, *b_qo;
  float *out_post, *out_prior, *out_deters;
  float *deter, *determ, *xact, *hact;
  float *SDyn, *SQ0, *SX0, *Abuf0, *Abuf1;
  int *sidxg;
};

// ---- A loaders ------------------------------------------------------------
struct LdPlain {
  const float* A; int lda;
  DEVINL const float* addr(int r, int k) const { return A + (size_t)r * lda + k; }
};
struct LdDyn {   // [dg(256 masked deter) | x(3072 activated)]
  const float* dm; const float* x; int blk;
  DEVINL const float* addr(int r, int k) const {
    return (k < 256) ? dm + (size_t)r * 2048 + blk * 256 + k
                     : x + (size_t)r * 3072 + (k - 256);
  }
};
struct LdQ0 {    // [deter(2048) | embed(1024)]
  const float* det; const float* emb; int t;
  DEVINL const float* addr(int r, int k) const {
    return (k < 2048) ? det + (size_t)r * 2048 + k
                      : emb + ((size_t)r * 64 + t) * 1024 + (k - 2048);
  }
};

#define FMA4(A, S, W) { (A)[0]=fmaf((S),(W)[0],(A)[0]); (A)[1]=fmaf((S),(W)[1],(A)[1]); \
                        (A)[2]=fmaf((S),(W)[2],(A)[2]); (A)[3]=fmaf((S),(W)[3],(A)[3]); }

// ---- GEMM (K-chunked, slab output): 256 cols x 32 rows x (NBLK*64) K ------
template <int NBLK, typename LA>
DEVINL void gemm_tile(LA la, const float* __restrict__ W, int ldw, int wcb,
                      int k0, float* __restrict__ slab, int sst, int scb,
                      const float* __restrict__ bias, float* As) {
  const int tid = threadIdx.x;
  const int c4 = (tid & 63) * 4;
  const int rg = (tid >> 6) * 8;
  const int srr = tid & 31;
  const int skk = (tid >> 5) * 8;
  f32x4 acc[8];
#pragma unroll
  for (int i = 0; i < 8; ++i) acc[i] = (f32x4){0.f, 0.f, 0.f, 0.f};
  const float* ap = la.addr(srr, k0 + skk);
  f32x4 cur0 = *(const f32x4*)ap;
  f32x4 cur1 = *(const f32x4*)(ap + 4);
#pragma unroll
  for (int b = 0; b < NBLK; ++b) {
    __syncthreads();
#pragma unroll
    for (int e = 0; e < 4; ++e) {
      As[(skk + e) * 36 + srr]     = cur0[e];
      As[(skk + 4 + e) * 36 + srr] = cur1[e];
    }
    f32x4 nxt0, nxt1;
    if (b + 1 < NBLK) {
      const float* np = la.addr(srr, k0 + (b + 1) * 64 + skk);
      nxt0 = *(const f32x4*)np;
      nxt1 = *(const f32x4*)(np + 4);
    }
    __syncthreads();
    const float* Wp = W + (size_t)(k0 + b * 64) * ldw + wcb + c4;
#pragma unroll 8
    for (int kk = 0; kk < 64; ++kk) {
      f32x4 w = *(const f32x4*)(Wp + (size_t)kk * ldw);
      const float* Ab = As + kk * 36 + rg;
      f32x4 alo = *(const f32x4*)(Ab);
      f32x4 ahi = *(const f32x4*)(Ab + 4);
      FMA4(acc[0], alo[0], w); FMA4(acc[1], alo[1], w);
      FMA4(acc[2], alo[2], w); FMA4(acc[3], alo[3], w);
      FMA4(acc[4], ahi[0], w); FMA4(acc[5], ahi[1], w);
      FMA4(acc[6], ahi[2], w); FMA4(acc[7], ahi[3], w);
    }
    if (b + 1 < NBLK) { cur0 = nxt0; cur1 = nxt1; }
  }
  f32x4 bv = (f32x4){0.f, 0.f, 0.f, 0.f};
  if (bias) bv = *(const f32x4*)(bias + wcb + c4);
#pragma unroll
  for (int i = 0; i < 8; ++i) {
    f32x4 o = acc[i] + bv;
    *(f32x4*)(slab + (size_t)(rg + i) * sst + scb + c4) = o;
  }
}

// ---- GEMM (full-K, direct output + bias): for batched epilogue ------------
template <typename LA>
DEVINL void gemm_big(LA la, const float* __restrict__ W, int ldw, int wcb,
                     int nblk, float* __restrict__ outp, int ost,
                     const float* __restrict__ bias, float* As) {
  const int tid = threadIdx.x;
  const int c4 = (tid & 63) * 4;
  const int rg = (tid >> 6) * 8;
  const int srr = tid & 31;
  const int skk = (tid >> 5) * 8;
  f32x4 acc[8];
#pragma unroll
  for (int i = 0; i < 8; ++i) acc[i] = (f32x4){0.f, 0.f, 0.f, 0.f};
  const float* ap = la.addr(srr, skk);
  f32x4 cur0 = *(const f32x4*)ap;
  f32x4 cur1 = *(const f32x4*)(ap + 4);
  f32x4 nxt0, nxt1;
  for (int b = 0; b < nblk; ++b) {
    __syncthreads();
#pragma unroll
    for (int e = 0; e < 4; ++e) {
      As[(skk + e) * 36 + srr]     = cur0[e];
      As[(skk + 4 + e) * 36 + srr] = cur1[e];
    }
    if (b + 1 < nblk) {
      const float* np = la.addr(srr, (b + 1) * 64 + skk);
      nxt0 = *(const f32x4*)np;
      nxt1 = *(const f32x4*)(np + 4);
    }
    __syncthreads();
    const float* Wp = W + (size_t)(b * 64) * ldw + wcb + c4;
#pragma unroll 8
    for (int kk = 0; kk < 64; ++kk) {
      f32x4 w = *(const f32x4*)(Wp + (size_t)kk * ldw);
      const float* Ab = As + kk * 36 + rg;
      f32x4 alo = *(const f32x4*)(Ab);
      f32x4 ahi = *(const f32x4*)(Ab + 4);
      FMA4(acc[0], alo[0], w); FMA4(acc[1], alo[1], w);
      FMA4(acc[2], alo[2], w); FMA4(acc[3], alo[3], w);
      FMA4(acc[4], ahi[0], w); FMA4(acc[5], ahi[1], w);
      FMA4(acc[6], ahi[2], w); FMA4(acc[7], ahi[3], w);
    }
    if (b + 1 < nblk) { cur0 = nxt0; cur1 = nxt1; }
  }
  f32x4 bv = *(const f32x4*)(bias + wcb + c4);
#pragma unroll
  for (int i = 0; i < 8; ++i) {
    f32x4 o = acc[i] + bv;
    *(f32x4*)(outp + (size_t)(rg + i) * ost + wcb + c4) = o;
  }
}

// ---- finalizer: y = sum chunks (regs, ascending), RMS, SiLU ---------------
DEVINL void act_fin(const float* __restrict__ slab, int N, int nch, int r,
                    const float* __restrict__ g, float* __restrict__ out,
                    float invN, float* red) {
  const int tid = threadIdx.x;
  const size_t cstr = (size_t)32 * N;
  const float* base = slab + (size_t)r * N + tid * 4;
  f32x4 y0 = (f32x4){0.f, 0.f, 0.f, 0.f}, y1 = y0;
  for (int ch = 0; ch < nch; ++ch)
    y0 += *(const f32x4*)(base + (size_t)ch * cstr);
  float ss = y0[0]*y0[0] + y0[1]*y0[1] + y0[2]*y0[2] + y0[3]*y0[3];
  if (N == 2048) {
    for (int ch = 0; ch < nch; ++ch)
      y1 += *(const f32x4*)(base + 1024 + (size_t)ch * cstr);
    ss += y1[0]*y1[0] + y1[1]*y1[1] + y1[2]*y1[2] + y1[3]*y1[3];
  }
#pragma unroll
  for (int o = 32; o > 0; o >>= 1) ss += __shfl_down(ss, o, 64);
  if ((tid & 63) == 0) red[tid >> 6] = ss;
  __syncthreads();
  if (tid == 0)
    red[4] = 1.f / sqrtf((red[0] + red[1] + red[2] + red[3]) * invN + 1e-6f);
  __syncthreads();
  const float sc = red[4];
  {
    f32x4 gg = *(const f32x4*)(g + tid * 4);
    f32x4 v = y0 * sc * gg;
#pragma unroll
    for (int k = 0; k < 4; ++k) v[k] = v[k] / (1.f + expf(-v[k]));
    *(f32x4*)(out + tid * 4) = v;
  }
  if (N == 2048) {
    f32x4 gg = *(const f32x4*)(g + 1024 + tid * 4);
    f32x4 v = y1 * sc * gg;
#pragma unroll
    for (int k = 0; k < 4; ++k) v[k] = v[k] / (1.f + expf(-v[k]));
    *(f32x4*)(out + 1024 + tid * 4) = v;
  }
}

DEVINL float sigm(float x) { return 1.f / (1.f + expf(-x)); }

// ---- x2 (action) pre-act + RMS + SiLU for row r, step tt ------------------
DEVINL void x2_row(const RPtrs& p, int tt, int r, float m, float* red) {
  const int tid = threadIdx.x;
  const int c0 = tid * 4;
  const float* arow = p.action + ((size_t)r * 64 + tt) * 16;
  f32x4 s2 = *(const f32x4*)(p.b_in_act + c0);
#pragma unroll
  for (int ii = 0; ii < 16; ++ii) {
    float av = arow[ii] * m;
    av = av / fmaxf(fabsf(av), 1.f);
    f32x4 wv = *(const f32x4*)(p.W_in_act + ii * 1024 + c0);
    FMA4(s2, av, wv);
  }
  float ss = s2[0]*s2[0] + s2[1]*s2[1] + s2[2]*s2[2] + s2[3]*s2[3];
#pragma unroll
  for (int o = 32; o > 0; o >>= 1) ss += __shfl_down(ss, o, 64);
  if ((tid & 63) == 0) red[tid >> 6] = ss;
  __syncthreads();
  if (tid == 0)
    red[4] = 1.f / sqrtf((red[0] + red[1] + red[2] + red[3]) * (1.f / 1024.f) + 1e-6f);
  __syncthreads();
  float sc = red[4];
  f32x4 gg = *(const f32x4*)(p.g_in_act + c0);
  f32x4 v = s2 * sc * gg;
#pragma unroll
  for (int k = 0; k < 4; ++k) v[k] = v[k] / (1.f + expf(-v[k]));
  *(f32x4*)(p.xact + (size_t)r * 3072 + 2048 + c0) = v;
}

// ---- bias-only pre-act + RMS + SiLU (for t=0: determ=0, stoch=0) ----------
DEVINL void bias_row(const float* __restrict__ b, const float* __restrict__ g,
                     float* __restrict__ out, float* red) {
  const int tid = threadIdx.x;
  const int c0 = tid * 4;
  f32x4 pre = *(const f32x4*)(b + c0);
  float ss = pre[0]*pre[0] + pre[1]*pre[1] + pre[2]*pre[2] + pre[3]*pre[3];
#pragma unroll
  for (int o = 32; o > 0; o >>= 1) ss += __shfl_down(ss, o, 64);
  if ((tid & 63) == 0) red[tid >> 6] = ss;
  __syncthreads();
  if (tid == 0)
    red[4] = 1.f / sqrtf((red[0] + red[1] + red[2] + red[3]) * (1.f / 1024.f) + 1e-6f);
  __syncthreads();
  float sc = red[4];
  f32x4 gg = *(const f32x4*)(g + c0);
  f32x4 v = pre * sc * gg;
#pragma unroll
  for (int k = 0; k < 4; ++k) v[k] = v[k] / (1.f + expf(-v[k]));
  *(f32x4*)(out + c0) = v;
}

// ===========================================================================
// K0: init + prologue. grid 512: WGs 0-255 zero state; WGs 480-511 xact(0)
__global__ __launch_bounds__(256) void k_init(RPtrs p) {
  __shared__ float red[8];
  const int wg = blockIdx.x;
  size_t i = (size_t)wg * 256 + threadIdx.x;
  if (i < 65536) { p.deter[i] = 0.f; p.determ[i] = 0.f; }
  if (wg >= 480) {
    const int r = wg - 480;
    bias_row(p.b_in_deter, p.g_in_deter, p.xact + (size_t)r * 3072, red);
    __syncthreads();
    bias_row(p.b_in_stoch, p.g_in_stoch, p.xact + (size_t)r * 3072 + 1024, red);
    __syncthreads();
    float m = p.is_first[r * 64] ? 0.f : 1.f;
    x2_row(p, 0, r, m, red);
  }
}

// K1: dyn. grid 208
__global__ __launch_bounds__(256, 2) void k_dyn(RPtrs p, int t) {
  __shared__ __align__(16) float As[2304];
  const int wg = blockIdx.x;
  int blk = wg / 26, kc = wg % 26;  // KC=128
  LdDyn la{p.determ, p.xact, blk};
  gemm_tile<2>(la, p.W_dyn + (size_t)blk * 851968, 256, 0, kc * 128,
               p.SDyn + (size_t)kc * 65536, 2048, blk * 256,
               kc == 0 ? p.b_dyn + blk * 256 : nullptr, As);
}

// K2: dynfin. grid 32
__global__ __launch_bounds__(256, 2) void k_dynfin(RPtrs p) {
  __shared__ float red[8];
  act_fin(p.SDyn, 2048, 26, blockIdx.x, p.g_dyn,
          p.hact + (size_t)blockIdx.x * 2048, 1.f / 2048.f, red);
}

// K3: gru. grid 128
__global__ __launch_bounds__(256, 2) void k_gru(RPtrs p, int t) {
  __shared__ float Al[8704];
  const int wg = blockIdx.x;
  const int blk = wg >> 4, jch = wg & 15;
  const int tid = threadIdx.x;
  {
    const float* hp = p.hact + blk * 256 + tid;
#pragma unroll
    for (int jb = 0; jb < 32; ++jb)
      Al[tid * 34 + jb] = hp[(size_t)jb * 2048];
  }
  __syncthreads();
  const int j = tid & 15, rg = tid >> 4;
  const int r0 = rg * 2;
  const int jcol = jch * 16 + j;
  const float* Wg = p.W_gru + (size_t)blk * 196608 + jcol;
  float r0a = 0, r1a = 0, c0a = 0, c1a = 0, u0a = 0, u1a = 0;
#pragma unroll 4
  for (int kk = 0; kk < 256; ++kk) {
    float wr = Wg[(size_t)kk * 768];
    float wc = Wg[(size_t)kk * 768 + 256];
    float wu = Wg[(size_t)kk * 768 + 512];
    float ax = Al[kk * 34 + r0], ay = Al[kk * 34 + r0 + 1];
    r0a = fmaf(ax, wr, r0a); r1a = fmaf(ay, wr, r1a);
    c0a = fmaf(ax, wc, c0a); c1a = fmaf(ay, wc, c1a);
    u0a = fmaf(ax, wu, u0a); u1a = fmaf(ay, wu, u1a);
  }
  const int col = blk * 256 + jcol;
  const float br = p.b_gru[blk * 768 + jcol];
  const float bc = p.b_gru[blk * 768 + 256 + jcol];
  const float bu = p.b_gru[blk * 768 + 512 + jcol];
#pragma unroll
  for (int rr = 0; rr < 2; ++rr) {
    int r = r0 + rr;
    float gr = (rr ? r1a : r0a) + br;
    float gc = (rr ? c1a : c0a) + bc;
    float gu = (rr ? u1a : u0a) + bu;
    float rs = sigm(gr);
    float cc = tanhf(rs * gc);
    float uu = sigm(gu - 1.f);
    float dg = p.determ[(size_t)r * 2048 + col];
    float nd = uu * cc + (1.f - uu) * dg;
    p.deter[(size_t)r * 2048 + col] = nd;
    p.out_deters[((size_t)r * 64 + t) * 2048 + col] = nd;
    float mn = 0.f;
    if (t + 1 < 64) mn = p.is_first[r * 64 + (t + 1)] ? 0.f : 1.f;
    p.determ[(size_t)r * 2048 + col] = nd * mn;
  }
}

// K4: q0 (0-95) + x0(t+1) (96-159). grid 160
__global__ __launch_bounds__(256, 2) void k_q0x0(RPtrs p, int t) {
  __shared__ __align__(16) float As[2304];
  const int wg = blockIdx.x;
  if (wg < 96) {
    int ct = wg & 3, kc = wg >> 2;   // kc 0..23, KC=128, K=3072
    LdQ0 la{p.deter, p.embed, t};
    gemm_tile<2>(la, p.W_q0, 1024, ct * 256, kc * 128,
                 p.SQ0 + (size_t)kc * 32768, 1024, ct * 256,
                 kc == 0 ? p.b_q0 : nullptr, As);
  } else {
    if (t >= 63) return;
    int i = wg - 96, ct = i & 3, kc = i >> 2;   // kc 0..15, K=2048
    LdPlain la{p.determ, 2048};
    gemm_tile<2>(la, p.W_in_deter, 1024, ct * 256, kc * 128,
                 p.SX0 + (size_t)kc * 32768, 1024, ct * 256,
                 kc == 0 ? p.b_in_deter : nullptr, As);
  }
}

// K5: qo256. WG = (row r = wg>>3, col-chunk ch = wg&7 of 128 cols).
// q0fin for row r (redundant x8), chunked GEMV over W_qo[:, ch*128..],
// write post logits + local argmax (4 groups) -> sidxg. grid 256
__global__ __launch_bounds__(256, 2) void k_qo256(RPtrs p, int t) {
  __shared__ __align__(16) float smem[2184];
  float* qrow = smem;             // 1024
  float* pbuf = smem + 1024;      // 1024
  float* ybuf = smem + 2048;      // 128
  float* red  = smem + 2176;      // 8
  const int wg = blockIdx.x;
  const int r = wg >> 3, ch = wg & 7;
  const int tid = threadIdx.x;
  const int c0 = tid * 4;
  {  // q0fin -> qrow (same ascending chunk order as R9's act_fin)
    const float* base = p.SQ0 + (size_t)r * 1024 + c0;
    f32x4 y = (f32x4){0.f, 0.f, 0.f, 0.f};
#pragma unroll
    for (int cc = 0; cc < 24; ++cc) y += *(const f32x4*)(base + (size_t)cc * 32768);
    float ss = y[0]*y[0] + y[1]*y[1] + y[2]*y[2] + y[3]*y[3];
#pragma unroll
    for (int o = 32; o > 0; o >>= 1) ss += __shfl_down(ss, o, 64);
    if ((tid & 63) == 0) red[tid >> 6] = ss;
    __syncthreads();
    if (tid == 0)
      red[4] = 1.f / sqrtf((red[0] + red[1] + red[2] + red[3]) * (1.f / 1024.f) + 1e-6f);
    __syncthreads();
    float sc = red[4];
    f32x4 gg = *(const f32x4*)(p.g_q0 + c0);
    f32x4 v = y * sc * gg;
#pragma unroll
    for (int k = 0; k < 4; ++k) v[k] = v[k] / (1.f + expf(-v[k]));
    *(f32x4*)(qrow + c0) = v;
  }
  __syncthreads();
  const int cg = tid & 31, ks = tid >> 5;
  {  // GEMV k-partials: thread covers cols [ch*128+cg*4, +4), k in [ks*128,+128)
    f32x4 acc = (f32x4){0.f, 0.f, 0.f, 0.f};
    const float* Wq = p.W_qo + ch * 128 + cg * 4;
    const float* qr = qrow + ks * 128;
#pragma unroll 8
    for (int k = 0; k < 128; ++k) {
      f32x4 wv = *(const f32x4*)(Wq + (size_t)(ks * 128 + k) * 1024);
      FMA4(acc, qr[k], wv);
    }
    *(f32x4*)(pbuf + (ks * 32 + cg) * 4) = acc;
  }
  __syncthreads();
  if (tid < 32) {   // reduce 8 k-segments (ascending), add bias, emit
    f32x4 s = *(const f32x4*)(p.b_qo + ch * 128 + tid * 4);
#pragma unroll
    for (int k2 = 0; k2 < 8; ++k2) s += *(const f32x4*)(pbuf + (k2 * 32 + tid) * 4);
    *(f32x4*)(p.out_post + ((size_t)r * 64 + t) * 1024 + ch * 128 + tid * 4) = s;
    *(f32x4*)(ybuf + tid * 4) = s;
  }
  __syncthreads();
  if (t < 63 && tid < 4) {   // groups g = ch*4 + tid (32 cols each, chunk-local)
    const float* rb = ybuf + tid * 32;
    float best = rb[0]; int bi = 0;
#pragma unroll
    for (int c = 1; c < 32; ++c) {
      float v = rb[c];
      if (v > best) { best = v; bi = c; }   // strict > keeps first index
    }
    p.sidxg[r * 32 + ch * 4 + tid] = bi;
  }
}

// K6: finx12 (t<63 only). WGs 0-31: x1/x2(t+1); WGs 32-63: x0fin(t+1). grid 64
__global__ __launch_bounds__(256, 2) void k_finx12(RPtrs p, int t) {
  __shared__ float red[8];
  __shared__ int sidx[32];
  const int wg = blockIdx.x;
  const int tid = threadIdx.x;
  if (wg >= 32) {
    act_fin(p.SX0, 1024, 16, wg - 32, p.g_in_deter,
            p.xact + (size_t)(wg - 32) * 3072, 1.f / 1024.f, red);
    return;
  }
  const int r = wg;
  if (tid < 32) sidx[tid] = p.sidxg[r * 32 + tid] & 31;
  __syncthreads();
  const float m = p.is_first[r * 64 + t + 1] ? 0.f : 1.f;
  const int c0 = tid * 4;
  f32x4 s1 = (f32x4){0.f, 0.f, 0.f, 0.f};
  if (m != 0.f) {
    for (int g = 0; g < 32; ++g)
      s1 += *(const f32x4*)(p.W_in_stoch + (size_t)(g * 32 + sidx[g]) * 1024 + c0);
  }
  f32x4 pre = *(const f32x4*)(p.b_in_stoch + c0) + s1 * m;
  float ss = pre[0]*pre[0] + pre[1]*pre[1] + pre[2]*pre[2] + pre[3]*pre[3];
#pragma unroll
  for (int o = 32; o > 0; o >>= 1) ss += __shfl_down(ss, o, 64);
  if ((tid & 63) == 0) red[tid >> 6] = ss;
  __syncthreads();
  if (tid == 0)
    red[4] = 1.f / sqrtf((red[0] + red[1] + red[2] + red[3]) * (1.f / 1024.f) + 1e-6f);
  __syncthreads();
  {
    float sc = red[4];
    f32x4 gg = *(const f32x4*)(p.g_in_stoch + c0);
    f32x4 v = pre * sc * gg;
#pragma unroll
    for (int k = 0; k < 4; ++k) v[k] = v[k] / (1.f + expf(-v[k]));
    *(f32x4*)(p.xact + (size_t)r * 3072 + 1024 + c0) = v;
  }
  __syncthreads();
  x2_row(p, t + 1, r, m, red);
}

// ---- epilogue: batched prior over all 2048 (b,t) rows ---------------------
__global__ __launch_bounds__(256, 2) void kb_p0(RPtrs p) {
  __shared__ __align__(16) float As[2304];
  int rb = blockIdx.x >> 2, ct = blockIdx.x & 3;
  LdPlain la{p.out_deters + (size_t)rb * 32 * 2048, 2048};
  gemm_big(la, p.W_p0, 1024, ct * 256, 32,
           p.Abuf0 + (size_t)rb * 32 * 1024, 1024, p.b_p0, As);
}
__global__ __launch_bounds__(256, 2) void kb_fin0(RPtrs p) {
  __shared__ float red[8];
  int r = blockIdx.x;
  act_fin(p.Abuf0, 1024, 1, r, p.g_p0, p.Abuf1 + (size_t)r * 1024,
          1.f / 1024.f, red);
}
__global__ __launch_bounds__(256, 2) void kb_p1(RPtrs p) {
  __shared__ __align__(16) float As[2304];
  int rb = blockIdx.x >> 2, ct = blockIdx.x & 3;
  LdPlain la{p.Abuf1 + (size_t)rb * 32 * 1024, 1024};
  gemm_big(la, p.W_p1, 1024, ct * 256, 16,
           p.Abuf0 + (size_t)rb * 32 * 1024, 1024, p.b_p1, As);
}
__global__ __launch_bounds__(256, 2) void kb_fin1(RPtrs p) {
  __shared__ float red[8];
  int r = blockIdx.x;
  act_fin(p.Abuf0, 1024, 1, r, p.g_p1, p.Abuf1 + (size_t)r * 1024,
          1.f / 1024.f, red);
}
__global__ __launch_bounds__(256, 2) void kb_po(RPtrs p) {
  __shared__ __align__(16) float As[2304];
  int rb = blockIdx.x >> 2, ct = blockIdx.x & 3;
  LdPlain la{p.Abuf1 + (size_t)rb * 32 * 1024, 1024};
  gemm_big(la, p.W_po, 1024, ct * 256, 16,
           p.out_prior + (size_t)rb * 32 * 1024, 1024, p.b_po, As);
}

// ===========================================================================
extern "C" void kernel_launch(void* const* d_in, const int* in_sizes, int n_in,
                              void* d_out, int out_size, void* d_ws,
                              size_t ws_size, hipStream_t stream) {
  RPtrs p;
  p.embed      = (const float*)d_in[0];
  p.action     = (const float*)d_in[1];
  p.is_first   = (const int*)d_in[2];
  p.W_in_deter = (const float*)d_in[3];  p.b_in_deter = (const float*)d_in[4];  p.g_in_deter = (const float*)d_in[5];
  p.W_in_stoch = (const float*)d_in[6];  p.b_in_stoch = (const float*)d_in[7];  p.g_in_stoch = (const float*)d_in[8];
  p.W_in_act   = (const float*)d_in[9];  p.b_in_act   = (const float*)d_in[10]; p.g_in_act   = (const float*)d_in[11];
  p.W_dyn      = (const float*)d_in[12]; p.b_dyn      = (const float*)d_in[13]; p.g_dyn      = (const float*)d_in[14];
  p.W_gru      = (const float*)d_in[15]; p.b_gru      = (const float*)d_in[16];
  p.W_p0       = (const float*)d_in[17]; p.b_p0       = (const float*)d_in[18]; p.g_p0       = (const float*)d_in[19];
  p.W_p1       = (const float*)d_in[20]; p.b_p1       = (const float*)d_in[21]; p.g_p1       = (const float*)d_in[22];
  p.W_po       = (const float*)d_in[23]; p.b_po       = (const float*)d_in[24];
  p.W_q0       = (const float*)d_in[25]; p.b_q0       = (const float*)d_in[26]; p.g_q0       = (const float*)d_in[27];
  p.W_qo       = (const float*)d_in[28]; p.b_qo       = (const float*)d_in[29];

  float* o = (float*)d_out;
  p.out_post   = o;               // [32][64][1024]
  p.out_prior  = o + 2097152;     // [32][64][1024]
  p.out_deters = o + 4194304;     // [32][64][2048]

  float* w = (float*)d_ws;
  // loop-era layout (all dead by epilogue):
  p.deter  = w;                   // 65536
  p.determ = w + 65536;           // 65536
  p.xact   = w + 131072;          // 98304   [32][3072]
  p.hact   = w + 229376;          // 65536
  p.SDyn   = w + 393216;          // 1703936 [26][32][2048]
  p.SQ0    = w + 2097152;         // 786432  [24][32][1024]
  p.SX0    = w + 2883584;         // 524288  [16][32][1024]
  // epilogue-era layout (reuses loop buffers; strictly launch-ordered):
  p.Abuf0  = w;                   // 2097152 [2048][1024]
  p.Abuf1  = w + 2097152;         // 2097152 [2048][1024]
  p.sidxg  = (int*)(w + 4194304); // 1024
  // total 4195328 floats ~= 16.8 MB

  k_init<<<512, 256, 0, stream>>>(p);
  for (int t = 0; t < 64; ++t) {
    k_dyn<<<208, 256, 0, stream>>>(p, t);
    k_dynfin<<<32, 256, 0, stream>>>(p);
    k_gru<<<128, 256, 0, stream>>>(p, t);
    k_q0x0<<<160, 256, 0, stream>>>(p, t);
    k_qo256<<<256, 256, 0, stream>>>(p, t);
    if (t < 63) k_finx12<<<64, 256, 0, stream>>>(p, t);
  }
  kb_p0<<<256, 256, 0, stream>>>(p);
  kb_fin0<<<2048, 256, 0, stream>>>(p);
  kb_p1<<<256, 256, 0, stream>>>(p);
  kb_fin1<<<2048, 256, 0, stream>>>(p);
  kb_po<<<256, 256, 0, stream>>>(p);
}